// Round 11
// baseline (146.125 us; speedup 1.0000x reference)
//
#include <hip/hip_runtime.h>
#include <math.h>

constexpr int N  = 50000;
constexpr int E  = 800000;
constexpr int F1 = 128;
constexpr int F2 = 16;
constexpr int BSHIFT  = 8;                        // 256-node buckets
constexpr int NBUCKET = (N + 255) >> BSHIFT;      // 196
constexpr int CHUNK   = 2048;                     // edges per scatter chunk
constexpr int CAP     = 6144;                     // per-bucket capacity
constexpr int SBLK    = (E + CHUNK - 1) / CHUNK;  // 391 scatter chunks
constexpr int TILES   = (N + 63) / 64;            // 782 gemm1 tiles (1 per block)

typedef unsigned short ushort_t;
typedef unsigned char  uchar_t;
typedef __bf16 bf16x8 __attribute__((ext_vector_type(8)));
typedef float  f32x4  __attribute__((ext_vector_type(4)));

static __device__ __forceinline__ float blo(unsigned u) { return __uint_as_float(u << 16); }
static __device__ __forceinline__ float bhi(unsigned u) { return __uint_as_float(u & 0xffff0000u); }
static __device__ __forceinline__ ushort_t to_bf(float f) { __bf16 h = (__bf16)f; return *(ushort_t*)&h; }
static __device__ __forceinline__ uchar_t to_fp8(float f) {
    return (uchar_t)(__builtin_amdgcn_cvt_pk_fp8_f32(f, f, 0, false) & 0xff);
}
template <int S>
static __device__ __forceinline__ float cf8(unsigned u) {
    return __builtin_amdgcn_cvt_f32_fp8(u, S);
}

// ---------- K1: GEMM1 x@W1 -> fp8 (blocks 0..781, 1 tile each) + chunk scatter ----------
// gemm role: x loads issued BEFORE W1->LDS staging (HBM latency hides under staging);
//            782 blocks (vs 391x2) doubles resident gemm waves -> 2x x-bytes in flight.
// scatter role (blocks 782..1172, light, backfills): LDS histogram -> scan -> bucket-sort
//            -> block-contiguous P2 write + per-(bucket,chunk) cnt/loff. No global atomics.
__global__ __launch_bounds__(256) void k_scatterP_gemm1(const int* __restrict__ row,
                                                        const int* __restrict__ col,
                                                        unsigned* __restrict__ P2,
                                                        int* __restrict__ cnt_g,
                                                        int* __restrict__ loff_g,
                                                        const float* __restrict__ x,
                                                        const float* __restrict__ W1,
                                                        uchar_t* __restrict__ h1q) {
    __shared__ __align__(16) char smem[F1 * 136 * 2];  // 34.8 KB
    int t = threadIdx.x;

    if (blockIdx.x >= TILES) {          // ---- scatter role: one chunk per block ----
        int* hist = (int*)smem;                  // [256]
        int* lcur = hist + 256;                  // [256]
        int* wtot = lcur + 256;                  // [8]
        unsigned* eb = (unsigned*)(wtot + 8);    // [2048]
        int j = blockIdx.x - TILES;
        int base = j * CHUNK;
        hist[t] = 0;
        __syncthreads();
        int ce[CHUNK / 256];
#pragma unroll
        for (int i = 0; i < CHUNK / 256; ++i) {
            int e = base + i * 256 + t;
            ce[i] = (e < E) ? col[e] : -1;
            if (ce[i] >= 0) atomicAdd(&hist[ce[i] >> BSHIFT], 1);
        }
        __syncthreads();
        {   // 256-thread exclusive scan
            int lane = t & 63, wid = t >> 6;
            int v = hist[t];
            int incl = v;
#pragma unroll
            for (int d = 1; d < 64; d <<= 1) {
                int u = __shfl_up(incl, d, 64);
                if (lane >= d) incl += u;
            }
            if (lane == 63) wtot[wid] = incl;
            __syncthreads();
            int wb = 0;
            for (int w = 0; w < wid; ++w) wb += wtot[w];
            int ex = wb + incl - v;
            lcur[t] = ex;
            if (t < NBUCKET) { cnt_g[t * SBLK + j] = v; loff_g[t * SBLK + j] = ex; }
        }
        __syncthreads();
#pragma unroll
        for (int i = 0; i < CHUNK / 256; ++i) {   // LDS bucket-sort
            int e = base + i * 256 + t;
            if (ce[i] >= 0) {
                int pos = atomicAdd(&lcur[ce[i] >> BSHIFT], 1);
                eb[pos] = ((unsigned)row[e] << BSHIFT) | (unsigned)(ce[i] & 255);
            }
        }
        __syncthreads();
        int total = min(CHUNK, E - base);
#pragma unroll
        for (int i = 0; i < CHUNK / 256; ++i) {   // block-contiguous, fully coalesced
            int k = i * 256 + t;
            if (k < total) P2[base + k] = eb[k];
        }
        return;
    }

    // ---- gemm1 role: one 64-row tile per block ----
    ushort_t* Wl = (ushort_t*)smem;              // [F1*136] bf16 W1^T
    int tile = blockIdx.x;
    int lane = t & 63, wv = t >> 6;
    int quad = lane >> 4, l15 = lane & 15;
    int arow = tile * 64 + wv * 16 + l15;
    int rclamp = min(arow, N - 1);

    // 1) issue all x loads first (8 float4 = 128 B/thread, independent)
    float4 xr[8];
    {
        const float* xp = x + (size_t)rclamp * F1 + quad * 8;
#pragma unroll
        for (int kk = 0; kk < 4; ++kk) {
            xr[kk * 2]     = *(const float4*)(xp + kk * 32);
            xr[kk * 2 + 1] = *(const float4*)(xp + kk * 32 + 4);
        }
    }
    // 2) W1[k][n] f32 -> Wl[n][k] bf16 (L2-hot after first block); hides x latency
    {
        int n = t & 127, kh = t >> 7;
#pragma unroll
        for (int j = 0; j < 8; ++j) {
            int k0 = (kh * 8 + j) * 8;
            bf16x8 w;
#pragma unroll
            for (int i2 = 0; i2 < 8; ++i2) w[i2] = (__bf16)W1[(k0 + i2) * F1 + n];
            *(bf16x8*)&Wl[n * 136 + k0] = w;
        }
    }
    __syncthreads();

    // 3) MFMA
    f32x4 acc[8] = {};
#pragma unroll
    for (int kk = 0; kk < 4; ++kk) {
        int k0 = kk * 32 + quad * 8;
        float4 u0 = xr[kk * 2];
        float4 u1 = xr[kk * 2 + 1];
        bf16x8 a;
        a[0] = (__bf16)u0.x; a[1] = (__bf16)u0.y; a[2] = (__bf16)u0.z; a[3] = (__bf16)u0.w;
        a[4] = (__bf16)u1.x; a[5] = (__bf16)u1.y; a[6] = (__bf16)u1.z; a[7] = (__bf16)u1.w;
#pragma unroll
        for (int ct = 0; ct < 8; ++ct) {
            bf16x8 bfr = *(const bf16x8*)&Wl[(ct * 16 + l15) * 136 + k0];
            acc[ct] = __builtin_amdgcn_mfma_f32_16x16x32_bf16(a, bfr, acc[ct], 0, 0, 0);
        }
    }
    int orow0 = tile * 64 + wv * 16 + quad * 4;
#pragma unroll
    for (int r = 0; r < 4; ++r) {
        int orow = orow0 + r;
        if (orow < N) {
#pragma unroll
            for (int ct = 0; ct < 8; ++ct)
                h1q[(size_t)orow * F1 + ct * 16 + l15] = to_fp8(acc[ct][r]);
        }
    }
}

// ---------- K2: per-bucket finalize, chunk-major (1024 thr, no binary search) ----------
__global__ __launch_bounds__(1024) void k_binFinal(const unsigned* __restrict__ P2,
                                                   const int* __restrict__ cnt_g,
                                                   const int* __restrict__ loff_g,
                                                   ushort_t* __restrict__ csr16,
                                                   int* __restrict__ seg_start,
                                                   int* __restrict__ counts,
                                                   float* __restrict__ dinv) {
    __shared__ int cS[SBLK];
    __shared__ int oS[SBLK];
    __shared__ int baseS[SBLK];
    __shared__ int wtot[16];
    __shared__ int cnt[256];
    __shared__ int cur[256];
    __shared__ unsigned eb2[CAP];
    int t = threadIdx.x;
    int b = blockIdx.x;
    int lo = b << BSHIFT;
    int lane = t & 63, wid = t >> 6;     // 16 waves
    if (t < SBLK) { cS[t] = cnt_g[b * SBLK + t]; oS[t] = loff_g[b * SBLK + t]; }
    if (t < 256) cnt[t] = 0;
    __syncthreads();
    int m;
    {   // exclusive scan over chunk counts (1024-padded)
        int v = (t < SBLK) ? cS[t] : 0;
        int incl = v;
#pragma unroll
        for (int d = 1; d < 64; d <<= 1) {
            int u = __shfl_up(incl, d, 64);
            if (lane >= d) incl += u;
        }
        if (lane == 63) wtot[wid] = incl;
        __syncthreads();
        int wb = 0;
        for (int w = 0; w < wid; ++w) wb += wtot[w];
        m = 0;
#pragma unroll
        for (int w = 0; w < 16; ++w) m += wtot[w];
        if (t < SBLK) baseS[t] = wb + incl - v;
    }
    __syncthreads();
    // chunk-major gather: wave wid handles chunks wid, wid+16, ... (direct addressing)
    for (int j = wid; j < SBLK; j += 16) {
        int c = cS[j];
        int src = j * CHUNK + oS[j];
        int dst = baseS[j];
        for (int k = lane; k < c; k += 64) {
            unsigned u = P2[src + k];
            eb2[dst + k] = u;
            atomicAdd(&cnt[u & 255], 1);
        }
    }
    __syncthreads();
    {   // node histogram scan -> seg_start/counts/dinv
        int v = (t < 256) ? cnt[t] : 0;
        int incl = v;
#pragma unroll
        for (int d = 1; d < 64; d <<= 1) {
            int u = __shfl_up(incl, d, 64);
            if (lane >= d) incl += u;
        }
        if (lane == 63) wtot[wid] = incl;
        __syncthreads();
        int wb = 0;
        for (int w = 0; w < wid; ++w) wb += wtot[w];
        if (t < 256) {
            int o = b * CAP + wb + incl - v;   // csr16 mirrors padded bucket layout
            cur[t] = o;
            if (lo + t < N) {
                seg_start[lo + t] = o;
                counts[lo + t]    = v;
                dinv[lo + t]      = rsqrtf((float)v + 1.f);
            }
        }
    }
    __syncthreads();
    for (int k = t; k < m; k += 1024) {
        unsigned u = eb2[k];
        int pos = atomicAdd(&cur[u & 255], 1);
        csr16[pos] = (ushort_t)(u >> BSHIFT);
    }
}

// ---------- K3: gather1 (4 chains/wave, chunk-pipelined) + fused GEMM2 ----------
__global__ __launch_bounds__(256) void k_gather1_gemm2(const uchar_t* __restrict__ h1q,
                                                       const int* __restrict__ seg_start,
                                                       const int* __restrict__ counts,
                                                       const ushort_t* __restrict__ csr16,
                                                       const float* __restrict__ dinv,
                                                       const float* __restrict__ W2,
                                                       const float* __restrict__ b1,
                                                       ushort_t* __restrict__ h2s) {
    __shared__ __align__(16) ushort_t W2l[F2 * 136];  // W2^T bf16 [n][k]
    __shared__ __align__(16) ushort_t T[16 * 136];    // 16 h1r rows, bf16
    __shared__ float dv[16];
    int t = threadIdx.x;
    for (int i = t; i < F1 * F2; i += 256) {   // W2 [128][16] f32 -> W2l[n][k]
        int k = i >> 4, n = i & 15;
        W2l[n * 136 + k] = to_bf(W2[i]);
    }
    int lane = t & 63, wv = t >> 6;
    int g = lane >> 4, l15 = lane & 15;
    int gbase = lane & 48;                 // g << 4
    int nl = wv * 4 + g;
    int c = blockIdx.x * 16 + nl;
    int cl = min(c, N - 1);

    float dc = 0.f;
    int s = seg_start[cl];
    int cnt = 0;
    if (c < N) { dc = dinv[c]; cnt = counts[c]; }
    uint2 wsf = *(const uint2*)(h1q + ((size_t)cl << 7) + (l15 << 3));
    float4 bL = ((const float4*)b1)[l15 * 2];
    float4 bH = ((const float4*)b1)[l15 * 2 + 1];
    int mcnt = cnt;
    mcnt = max(mcnt, __shfl_xor(mcnt, 16));
    mcnt = max(mcnt, __shfl_xor(mcnt, 32));

    float a0 = 0.f, a1 = 0.f, a2 = 0.f, a3 = 0.f;
    float a4 = 0.f, a5 = 0.f, a6 = 0.f, a7 = 0.f;

#define G1FLT(j_, jb_) { unsigned u = __shfl(pk, gbase + (jb_) + (j_));                     \
        e##j_ = __uint_as_float(u & 0xffff0000u);                                           \
        w##j_ = *(const uint2*)(h1q + ((size_t)(u & 0xffffu) << 7) + (l15 << 3)); }
#define G1ACC(j_) {                                                                         \
        a0 = fmaf(e##j_, cf8<0>(w##j_.x), a0); a1 = fmaf(e##j_, cf8<1>(w##j_.x), a1);       \
        a2 = fmaf(e##j_, cf8<2>(w##j_.x), a2); a3 = fmaf(e##j_, cf8<3>(w##j_.x), a3);       \
        a4 = fmaf(e##j_, cf8<0>(w##j_.y), a4); a5 = fmaf(e##j_, cf8<1>(w##j_.y), a5);       \
        a6 = fmaf(e##j_, cf8<2>(w##j_.y), a6); a7 = fmaf(e##j_, cf8<3>(w##j_.y), a7); }

    unsigned pk = 0;
    {   int k = l15;
        if (k < cnt) {
            int r = csr16[s + k];
            pk = ((unsigned)to_bf(dinv[r]) << 16) | (unsigned)r;
        }
    }
#pragma unroll 1
    for (int k0 = 0; k0 < mcnt; k0 += 16) {
        unsigned pknext = 0;
        {   int k = k0 + 16 + l15;   // next chunk's index+weight, issued early
            if (k < cnt) {
                int r = csr16[s + k];
                pknext = ((unsigned)to_bf(dinv[r]) << 16) | (unsigned)r;
            }
        }
        {   // flights 0..7
            uint2 w0, w1, w2, w3, w4, w5, w6, w7;
            float e0, e1, e2, e3, e4, e5, e6, e7;
            G1FLT(0, 0) G1FLT(1, 0) G1FLT(2, 0) G1FLT(3, 0)
            G1FLT(4, 0) G1FLT(5, 0) G1FLT(6, 0) G1FLT(7, 0)
            G1ACC(0) G1ACC(1) G1ACC(2) G1ACC(3)
            G1ACC(4) G1ACC(5) G1ACC(6) G1ACC(7)
        }
        if (k0 + 8 < mcnt) {   // flights 8..15
            uint2 w0, w1, w2, w3, w4, w5, w6, w7;
            float e0, e1, e2, e3, e4, e5, e6, e7;
            G1FLT(0, 8) G1FLT(1, 8) G1FLT(2, 8) G1FLT(3, 8)
            G1FLT(4, 8) G1FLT(5, 8) G1FLT(6, 8) G1FLT(7, 8)
            G1ACC(0) G1ACC(1) G1ACC(2) G1ACC(3)
            G1ACC(4) G1ACC(5) G1ACC(6) G1ACC(7)
        }
        pk = pknext;
    }
#undef G1FLT
#undef G1ACC

    {   // self term + bias + relu + pack -> T
        a0 = fmaf(dc, cf8<0>(wsf.x), a0); a1 = fmaf(dc, cf8<1>(wsf.x), a1);
        a2 = fmaf(dc, cf8<2>(wsf.x), a2); a3 = fmaf(dc, cf8<3>(wsf.x), a3);
        a4 = fmaf(dc, cf8<0>(wsf.y), a4); a5 = fmaf(dc, cf8<1>(wsf.y), a5);
        a6 = fmaf(dc, cf8<2>(wsf.y), a6); a7 = fmaf(dc, cf8<3>(wsf.y), a7);
        a0 = fmaxf(fmaf(dc, a0, bL.x), 0.f); a1 = fmaxf(fmaf(dc, a1, bL.y), 0.f);
        a2 = fmaxf(fmaf(dc, a2, bL.z), 0.f); a3 = fmaxf(fmaf(dc, a3, bL.w), 0.f);
        a4 = fmaxf(fmaf(dc, a4, bH.x), 0.f); a5 = fmaxf(fmaf(dc, a5, bH.y), 0.f);
        a6 = fmaxf(fmaf(dc, a6, bH.z), 0.f); a7 = fmaxf(fmaf(dc, a7, bH.w), 0.f);
        uint4 pp;
        pp.x = (unsigned)to_bf(a0) | ((unsigned)to_bf(a1) << 16);
        pp.y = (unsigned)to_bf(a2) | ((unsigned)to_bf(a3) << 16);
        pp.z = (unsigned)to_bf(a4) | ((unsigned)to_bf(a5) << 16);
        pp.w = (unsigned)to_bf(a6) | ((unsigned)to_bf(a7) << 16);
        *(uint4*)&T[nl * 136 + (l15 << 3)] = pp;
        if (l15 == 0) dv[nl] = dc;
    }
    __syncthreads();

    if (wv == 0) {   // 16x16 tile: T(16x128) @ W2l^T(128x16)
        int quad = lane >> 4;
        f32x4 acc = {};
#pragma unroll
        for (int kk = 0; kk < 4; ++kk) {
            int k0 = kk * 32 + quad * 8;
            bf16x8 a = *(const bf16x8*)&T[l15 * 136 + k0];
            bf16x8 bfr = *(const bf16x8*)&W2l[l15 * 136 + k0];
            acc = __builtin_amdgcn_mfma_f32_16x16x32_bf16(a, bfr, acc, 0, 0, 0);
        }
#pragma unroll
        for (int r = 0; r < 4; ++r) {
            int rw = quad * 4 + r;
            int gn = blockIdx.x * 16 + rw;
            if (gn < N) h2s[(size_t)gn * F2 + l15] = to_bf(acc[r] * dv[rw]);
        }
    }
}

// ---------- K4: gather2 + log_softmax (8 lanes/node, 16-deep pipeline) ----------
__global__ __launch_bounds__(256) void k_gather2(const ushort_t* __restrict__ h2s,
                                                 const int* __restrict__ seg_start,
                                                 const int* __restrict__ counts,
                                                 const ushort_t* __restrict__ csr16,
                                                 const float* __restrict__ dinv,
                                                 const float* __restrict__ b2,
                                                 float* __restrict__ out) {
    int idx = blockIdx.x * 256 + threadIdx.x;
    int node = idx >> 3, sub = idx & 7;
    if (node >= N) return;
    int lane = threadIdx.x & 63;
    int gb = lane & 56;
    int s = seg_start[node], cntc = counts[node];
    float dc = dinv[node];
    float2 bb = ((const float2*)b2)[sub];
    unsigned us = ((const unsigned*)(h2s + (size_t)node * F2))[sub];
    float ax = 0.f, ay = 0.f;

#define G2L0(n_) { int src = gb | (n_); int r = __shfl(rl0, src);                           \
        w##n_ = ((const unsigned*)(h2s + (size_t)r * F2))[sub]; if ((n_) >= rem) w##n_ = 0u; }
#define G2L1(n_) { int src = gb | ((n_) - 8); int r = __shfl(rl1, src);                     \
        w##n_ = ((const unsigned*)(h2s + (size_t)r * F2))[sub]; if ((n_) >= rem) w##n_ = 0u; }

    int rl0 = 0, rl1 = 0;
    if (sub < cntc) rl0 = csr16[s + sub];
    if (8 + sub < cntc) rl1 = csr16[s + 8 + sub];
#pragma unroll 1
    for (int j0 = 0; j0 < cntc; j0 += 16) {
        int rem = cntc - j0;
        int rn0 = 0, rn1 = 0;
        int j2 = j0 + 16;
        if (j2 + sub < cntc) rn0 = csr16[s + j2 + sub];
        if (j2 + 8 + sub < cntc) rn1 = csr16[s + j2 + 8 + sub];
        unsigned w0, w1, w2, w3, w4, w5, w6, w7, w8, w9, w10, w11, w12, w13, w14, w15;
        G2L0(0) G2L0(1) G2L0(2) G2L0(3) G2L0(4) G2L0(5) G2L0(6) G2L0(7)
        G2L1(8) G2L1(9) G2L1(10) G2L1(11) G2L1(12) G2L1(13) G2L1(14) G2L1(15)
        ax += (((blo(w0) + blo(w1)) + (blo(w2) + blo(w3))) +
               ((blo(w4) + blo(w5)) + (blo(w6) + blo(w7)))) +
              (((blo(w8) + blo(w9)) + (blo(w10) + blo(w11))) +
               ((blo(w12) + blo(w13)) + (blo(w14) + blo(w15))));
        ay += (((bhi(w0) + bhi(w1)) + (bhi(w2) + bhi(w3))) +
               ((bhi(w4) + bhi(w5)) + (bhi(w6) + bhi(w7)))) +
              (((bhi(w8) + bhi(w9)) + (bhi(w10) + bhi(w11))) +
               ((bhi(w12) + bhi(w13)) + (bhi(w14) + bhi(w15))));
        rl0 = rn0; rl1 = rn1;
    }
#undef G2L0
#undef G2L1
    ax += blo(us);
    ay += bhi(us);
    float v0 = fmaf(dc, ax, bb.x);
    float v1 = fmaf(dc, ay, bb.y);
    float mx = fmaxf(v0, v1);
#pragma unroll
    for (int m = 1; m < 8; m <<= 1) mx = fmaxf(mx, __shfl_xor(mx, m));
    float sm = expf(v0 - mx) + expf(v1 - mx);
#pragma unroll
    for (int m = 1; m < 8; m <<= 1) sm += __shfl_xor(sm, m);
    float lse = mx + logf(sm);
    float2 o;
    o.x = v0 - lse;
    o.y = v1 - lse;
    ((float2*)(out + (size_t)node * F2))[sub] = o;
}

extern "C" void kernel_launch(void* const* d_in, const int* in_sizes, int n_in,
                              void* d_out, int out_size, void* d_ws, size_t ws_size,
                              hipStream_t stream) {
    const float* x  = (const float*)d_in[0];
    const int*   ei = (const int*)d_in[1];
    const float* W1 = (const float*)d_in[2];
    const float* b1 = (const float*)d_in[3];
    const float* W2 = (const float*)d_in[4];
    const float* b2 = (const float*)d_in[5];
    const int* rowp = ei;
    const int* colp = ei + E;

    char* ws = (char*)d_ws;
    unsigned* P2        = (unsigned*)ws; ws += (size_t)SBLK * CHUNK * 4;    // 3.2 MB
    int*      cnt_g     = (int*)ws;      ws += (size_t)NBUCKET * SBLK * 4;  // 306 KB
    int*      loff_g    = (int*)ws;      ws += (size_t)NBUCKET * SBLK * 4;  // 306 KB
    ushort_t* csr16     = (ushort_t*)ws; ws += (size_t)NBUCKET * CAP * 2;   // 2.4 MB
    int*      seg_start = (int*)ws;      ws += (size_t)N * 4;
    int*      counts    = (int*)ws;      ws += (size_t)N * 4;
    float*    dinvp     = (float*)ws;    ws += (size_t)N * 4;
    uchar_t*  h1q       = (uchar_t*)ws;  ws += (size_t)N * F1;              // 6.4 MB
    ushort_t* h2s       = (ushort_t*)ws; ws += (size_t)N * F2 * 2;          // 1.6 MB

    k_scatterP_gemm1<<<TILES + SBLK, 256, 0, stream>>>(rowp, colp, P2, cnt_g, loff_g,
                                                       x, W1, h1q);
    k_binFinal<<<NBUCKET, 1024, 0, stream>>>(P2, cnt_g, loff_g, csr16, seg_start,
                                             counts, dinvp);
    k_gather1_gemm2<<<(N + 15) / 16, 256, 0, stream>>>(h1q, seg_start, counts, csr16,
                                                       dinvp, W2, b1, h2s);
    k_gather2<<<((size_t)N * 8 + 255) / 256, 256, 0, stream>>>(h2s, seg_start, counts, csr16,
                                                               dinvp, b2, (float*)d_out);
}